// Round 11
// baseline (23.175 us; speedup 1.0000x reference)
//
#include <hip/hip_runtime.h>
#include <cstdint>
#include <cstddef>

#define B_ 32
#define V_ 8
#define S_ 4096
#define E_ 64
#define T_ 1020     // len(arange(0, S-WIN, STEP))
#define TT 32       // tokens per block
#define SLP 200     // e-tile row stride elems (need >=140); 400B row

typedef __bf16 bf16_t;
typedef bf16_t bf16x8 __attribute__((ext_vector_type(8)));
typedef float f32x4 __attribute__((ext_vector_type(4)));
typedef unsigned long long u64;
typedef u64 u64x2 __attribute__((ext_vector_type(2)));

// ---- prep: w2sw swizzled bf16 so a wave's B-fragment is one coalesced 1KB load ----
// elem ((kk*4 + nt)*64 + l)*8 + j  =  W2[f = kk*32 + (l>>4)*8 + j][n = nt*16 + (l&15)]
__global__ __launch_bounds__(256) void prep_kernel(const float* __restrict__ W2,
                                                   bf16_t* __restrict__ w2sw) {
  const int q = blockIdx.x * 256 + threadIdx.x;      // 8192 quads of 8 elems
  const int l = q & 63, nt = (q >> 6) & 3, kk = q >> 8;
  const int fb = kk * 32 + (l >> 4) * 8;
  const int n = nt * 16 + (l & 15);
  bf16x8 v;
#pragma unroll
  for (int j = 0; j < 8; ++j) v[j] = (bf16_t)W2[(fb + j) * E_ + n];
  *reinterpret_cast<bf16x8*>(w2sw + (size_t)q * 8) = v;
}

// ---- fused: e-build (wave-uniform d, W1/b1 scalar-loaded) + pinned-preload K-loop ----
__global__ __launch_bounds__(256, 4) void fused_kernel(const float* __restrict__ x,
                                                       const float* __restrict__ W1,
                                                       const float* __restrict__ b1,
                                                       const bf16_t* __restrict__ w2sw,
                                                       const float* __restrict__ b2,
                                                       float* __restrict__ out) {
  __shared__ bf16_t et[E_ * SLP];   // 25.6 KB
  const int tid = threadIdx.x;
  const int b = blockIdx.y;
  const int t0 = blockIdx.x * TT;
  const int lane = tid & 63;
  const int wvu = __builtin_amdgcn_readfirstlane(tid >> 6);   // wave id, provably uniform
  const int l15 = lane & 15;
  const int g = lane >> 4;
  const int s0 = 4 * t0;

  // ---- issue ALL cold loads up front: x (24 VGPR), B kk<16 (64 VGPR, pinned) ----
  int sc[3];
#pragma unroll
  for (int k = 0; k < 3; ++k) {
    int s = s0 + lane + 64 * k;
    sc[k] = (s > S_ - 1) ? (S_ - 1) : s;   // clamp: only masked-token windows affected
  }
  float xv[V_][3];
#pragma unroll
  for (int v = 0; v < V_; ++v) {
    const float* xb = x + ((size_t)(b * V_ + v) << 12);
#pragma unroll
    for (int k = 0; k < 3; ++k) xv[v][k] = xb[sc[k]];
  }
  const bf16_t* bptr = w2sw + (((size_t)wvu * 64 + lane) << 3);   // +2048 elems per kk
  bf16x8 bpre[16];
#pragma unroll
  for (int kk = 0; kk < 16; ++kk) {
    bpre[kk] = *reinterpret_cast<const bf16x8*>(bptr + ((size_t)kk << 11));
    u64x2 t = __builtin_bit_cast(u64x2, bpre[kk]);
    asm volatile("" : "+v"(t[0]), "+v"(t[1]));   // pin: forbid sinking past this point
    bpre[kk] = __builtin_bit_cast(bf16x8, t);
  }

  // ---- e-build: wave wvu owns d in [16*wvu, 16*wvu+16); lane = s_local; 3 s-slots ----
  // W1/b1 addresses are wave-uniform -> s_load (scalar cache), off the VMEM/VGPR path.
  const int dbase = wvu * 16;
  const float* w1w = W1 + dbase;
  const float* b1w = b1 + dbase;
#pragma unroll
  for (int dd = 0; dd < 16; ++dd) {
    const float bb = b1w[dd];
    float a0 = bb, a1 = bb, a2 = bb;
#pragma unroll
    for (int v = 0; v < V_; ++v) {
      const float w = w1w[v * E_ + dd];
      a0 += xv[v][0] * w;
      a1 += xv[v][1] * w;
      a2 += xv[v][2] * w;
    }
    const int row = (dbase + dd) * SLP;
    et[row + lane]      = (bf16_t)floorf(a0);
    et[row + lane + 64] = (bf16_t)floorf(a1);
    if (lane < 12) et[row + lane + 128] = (bf16_t)floorf(a2);   // s_local 128..139
  }
  __syncthreads();

  // ---- K-loop: A from LDS e-tile; B from bpre (kk<16) then streamed (kk>=16) ----
  const char* etb = reinterpret_cast<const char*>(et);
  const uint32_t aoff = 400u * (g >> 1) + 8u * l15 + 16u * (g & 1);  // +800/kk, +128/mt
  const float bv = b2[wvu * 16 + l15];
  f32x4 acc0 = {bv, bv, bv, bv};
  f32x4 acc1 = {bv, bv, bv, bv};
#pragma unroll
  for (int kk = 0; kk < 16; ++kk) {
    const char* pa = etb + aoff + 800 * kk;
    union { u64 q[2]; bf16x8 v; } A0, A1;
    A0.q[0] = *reinterpret_cast<const u64*>(pa);
    A0.q[1] = *reinterpret_cast<const u64*>(pa + 8);
    A1.q[0] = *reinterpret_cast<const u64*>(pa + 128);
    A1.q[1] = *reinterpret_cast<const u64*>(pa + 136);
    acc0 = __builtin_amdgcn_mfma_f32_16x16x32_bf16(A0.v, bpre[kk], acc0, 0, 0, 0);
    acc1 = __builtin_amdgcn_mfma_f32_16x16x32_bf16(A1.v, bpre[kk], acc1, 0, 0, 0);
  }
#pragma unroll 8
  for (int kk = 16; kk < 32; ++kk) {
    const char* pa = etb + aoff + 800 * kk;
    union { u64 q[2]; bf16x8 v; } A0, A1;
    A0.q[0] = *reinterpret_cast<const u64*>(pa);
    A0.q[1] = *reinterpret_cast<const u64*>(pa + 8);
    A1.q[0] = *reinterpret_cast<const u64*>(pa + 128);
    A1.q[1] = *reinterpret_cast<const u64*>(pa + 136);
    const bf16x8 Bf = *reinterpret_cast<const bf16x8*>(bptr + ((size_t)kk << 11));
    acc0 = __builtin_amdgcn_mfma_f32_16x16x32_bf16(A0.v, Bf, acc0, 0, 0, 0);
    acc1 = __builtin_amdgcn_mfma_f32_16x16x32_bf16(A1.v, Bf, acc1, 0, 0, 0);
  }
  // ---- epilogue: D row = g*4+r (token), col = l15 (n); nontemporal stores ----
#pragma unroll
  for (int r = 0; r < 4; ++r) {
    const int t1 = t0 + g * 4 + r;
    if (t1 < T_)
      __builtin_nontemporal_store(floorf(acc0[r]),
                                  &out[((size_t)(b * T_ + t1)) * E_ + wvu * 16 + l15]);
    const int t2 = t0 + 16 + g * 4 + r;
    if (t2 < T_)
      __builtin_nontemporal_store(floorf(acc1[r]),
                                  &out[((size_t)(b * T_ + t2)) * E_ + wvu * 16 + l15]);
  }
}

extern "C" void kernel_launch(void* const* d_in, const int* in_sizes, int n_in,
                              void* d_out, int out_size, void* d_ws, size_t ws_size,
                              hipStream_t stream) {
  const float* x  = (const float*)d_in[0];
  const float* W1 = (const float*)d_in[1];
  const float* b1 = (const float*)d_in[2];
  const float* W2 = (const float*)d_in[3];
  const float* b2 = (const float*)d_in[4];
  float* out = (float*)d_out;

  bf16_t* w2sw = (bf16_t*)d_ws;   // 128 KiB swizzled bf16 W2

  hipLaunchKernelGGL(prep_kernel, dim3(32), dim3(256), 0, stream, W2, w2sw);
  hipLaunchKernelGGL(fused_kernel, dim3((T_ + TT - 1) / TT, B_), dim3(256), 0, stream,
                     x, W1, b1, w2sw, b2, out);
}

// Round 12
// 22.931 us; speedup vs baseline: 1.0106x; 1.0106x over previous
//
#include <hip/hip_runtime.h>
#include <cstdint>
#include <cstddef>

#define B_ 32
#define V_ 8
#define S_ 4096
#define E_ 64
#define T_ 1020     // len(arange(0, S-WIN, STEP))
#define TT 32       // tokens per block
#define SLP 200     // e-tile row stride elems (need >=140); 400B row

typedef __bf16 bf16_t;
typedef bf16_t bf16x8 __attribute__((ext_vector_type(8)));
typedef float f32x4 __attribute__((ext_vector_type(4)));
typedef unsigned long long u64;

// ---- prep: w2sw swizzled bf16 so a wave's B-fragment is one coalesced 1KB load ----
// elem ((kk*4 + nt)*64 + l)*8 + j  =  W2[f = kk*32 + (l>>4)*8 + j][n = nt*16 + (l&15)]
__global__ __launch_bounds__(256) void prep_kernel(const float* __restrict__ W2,
                                                   bf16_t* __restrict__ w2sw) {
  const int q = blockIdx.x * 256 + threadIdx.x;      // 8192 quads of 8 elems
  const int l = q & 63, nt = (q >> 6) & 3, kk = q >> 8;
  const int fb = kk * 32 + (l >> 4) * 8;
  const int n = nt * 16 + (l & 15);
  bf16x8 v;
#pragma unroll
  for (int j = 0; j < 8; ++j) v[j] = (bf16_t)W2[(fb + j) * E_ + n];
  *reinterpret_cast<bf16x8*>(w2sw + (size_t)q * 8) = v;
}

__device__ __forceinline__ uint32_t pack2bf(float a, float b) {
  union { bf16_t h[2]; uint32_t u; } p;
  p.h[0] = (bf16_t)a;
  p.h[1] = (bf16_t)b;
  return p.u;
}

// ---- fused: wave-uniform e-build (scalar W1/b1, packed b32 LDS writes) + R10 K-loop ----
__global__ __launch_bounds__(256, 4) void fused_kernel(const float* __restrict__ x,
                                                       const float* __restrict__ W1,
                                                       const float* __restrict__ b1,
                                                       const bf16_t* __restrict__ w2sw,
                                                       const float* __restrict__ b2,
                                                       float* __restrict__ out) {
  __shared__ bf16_t et[E_ * SLP];   // 25.6 KB
  const int tid = threadIdx.x;
  const int b = blockIdx.y;
  const int t0 = blockIdx.x * TT;
  const int lane = tid & 63;
  const int wvu = __builtin_amdgcn_readfirstlane(tid >> 6);   // wave id, uniform
  const int l15 = lane & 15;
  const int g = lane >> 4;
  const int s0 = 4 * t0;

  // ---- x loads: lane owns s-pair {s0+2*lane, +1} (+ tail pairs on lanes 0..5) ----
  // Main region max s = s0+127 <= 4095: never clamped. Tail (s_local 128..139) clamped.
  float2 xm[V_];
  float xt0[V_], xt1[V_];
  const bool htail = lane < 6;
  int sa = s0 + 128 + 2 * lane, sb = sa + 1;
  if (sa > S_ - 1) sa = S_ - 1;
  if (sb > S_ - 1) sb = S_ - 1;
#pragma unroll
  for (int v = 0; v < V_; ++v) {
    const float* xb = x + ((size_t)(b * V_ + v) << 12);
    xm[v] = *reinterpret_cast<const float2*>(xb + s0 + 2 * lane);
    xt0[v] = htail ? xb[sa] : 0.0f;
    xt1[v] = htail ? xb[sb] : 0.0f;
  }

  // ---- e-build: wave wvu owns d in [16*wvu, 16*wvu+16); W1/b1 via scalar loads ----
  char* etc = reinterpret_cast<char*>(et);
  const int dbase = wvu * 16;
#pragma unroll
  for (int dd = 0; dd < 16; ++dd) {
    const int d = dbase + dd;
    const float bb = b1[d];                  // wave-uniform -> s_load
    float a0 = bb, a1 = bb, c0 = bb, c1 = bb;
#pragma unroll
    for (int v = 0; v < V_; ++v) {
      const float w = W1[v * E_ + d];        // wave-uniform -> s_load
      a0 += xm[v].x * w;
      a1 += xm[v].y * w;
      c0 += xt0[v] * w;
      c1 += xt1[v] * w;
    }
    *reinterpret_cast<uint32_t*>(etc + d * 400 + 4 * lane) =
        pack2bf(floorf(a0), floorf(a1));
    if (htail)
      *reinterpret_cast<uint32_t*>(etc + d * 400 + 256 + 4 * lane) =
          pack2bf(floorf(c0), floorf(c1));
  }
  __syncthreads();

  // ---- K-loop (R10): A from LDS e-tile; B streamed from w2sw, unroll 8 ----
  const char* etb = reinterpret_cast<const char*>(et);
  const uint32_t aoff = 400u * (g >> 1) + 8u * l15 + 16u * (g & 1);  // +800/kk, +128/mt
  const bf16_t* bptr = w2sw + (((size_t)wvu * 64 + lane) << 3);      // +2048 elems per kk
  const float bv = b2[wvu * 16 + l15];
  f32x4 acc0 = {bv, bv, bv, bv};
  f32x4 acc1 = {bv, bv, bv, bv};
#pragma unroll 8
  for (int kk = 0; kk < 32; ++kk) {
    const char* pa = etb + aoff + 800 * kk;
    union { u64 q[2]; bf16x8 v; } A0, A1;
    A0.q[0] = *reinterpret_cast<const u64*>(pa);
    A0.q[1] = *reinterpret_cast<const u64*>(pa + 8);
    A1.q[0] = *reinterpret_cast<const u64*>(pa + 128);
    A1.q[1] = *reinterpret_cast<const u64*>(pa + 136);
    const bf16x8 Bf = *reinterpret_cast<const bf16x8*>(bptr + ((size_t)kk << 11));
    acc0 = __builtin_amdgcn_mfma_f32_16x16x32_bf16(A0.v, Bf, acc0, 0, 0, 0);
    acc1 = __builtin_amdgcn_mfma_f32_16x16x32_bf16(A1.v, Bf, acc1, 0, 0, 0);
  }
  // ---- epilogue: D row = g*4+r (token), col = l15 (n); nontemporal stores ----
#pragma unroll
  for (int r = 0; r < 4; ++r) {
    const int t1 = t0 + g * 4 + r;
    if (t1 < T_)
      __builtin_nontemporal_store(floorf(acc0[r]),
                                  &out[((size_t)(b * T_ + t1)) * E_ + wvu * 16 + l15]);
    const int t2 = t0 + 16 + g * 4 + r;
    if (t2 < T_)
      __builtin_nontemporal_store(floorf(acc1[r]),
                                  &out[((size_t)(b * T_ + t2)) * E_ + wvu * 16 + l15]);
  }
}

extern "C" void kernel_launch(void* const* d_in, const int* in_sizes, int n_in,
                              void* d_out, int out_size, void* d_ws, size_t ws_size,
                              hipStream_t stream) {
  const float* x  = (const float*)d_in[0];
  const float* W1 = (const float*)d_in[1];
  const float* b1 = (const float*)d_in[2];
  const float* W2 = (const float*)d_in[3];
  const float* b2 = (const float*)d_in[4];
  float* out = (float*)d_out;

  bf16_t* w2sw = (bf16_t*)d_ws;   // 128 KiB swizzled bf16 W2

  hipLaunchKernelGGL(prep_kernel, dim3(32), dim3(256), 0, stream, W2, w2sw);
  hipLaunchKernelGGL(fused_kernel, dim3((T_ + TT - 1) / TT, B_), dim3(256), 0, stream,
                     x, W1, b1, w2sw, b2, out);
}

// Round 13
// 21.934 us; speedup vs baseline: 1.0566x; 1.0455x over previous
//
#include <hip/hip_runtime.h>
#include <cstdint>
#include <cstddef>

#define B_ 32
#define V_ 8
#define S_ 4096
#define E_ 64
#define T_ 1020     // len(arange(0, S-WIN, STEP))
#define TT 32       // tokens per block
#define SLP 200     // e-tile row stride elems (need >=140); 400B row

typedef __bf16 bf16_t;
typedef bf16_t bf16x8 __attribute__((ext_vector_type(8)));
typedef float f32x4 __attribute__((ext_vector_type(4)));
typedef unsigned long long u64;

// ---- prep: w2sw swizzled bf16 so a wave's B-fragment is one coalesced 1KB load ----
// elem ((kk*4 + nt)*64 + l)*8 + j  =  W2[f = kk*32 + (l>>4)*8 + j][n = nt*16 + (l&15)]
__global__ __launch_bounds__(256) void prep_kernel(const float* __restrict__ W2,
                                                   bf16_t* __restrict__ w2sw) {
  const int q = blockIdx.x * 256 + threadIdx.x;      // 8192 quads of 8 elems
  const int l = q & 63, nt = (q >> 6) & 3, kk = q >> 8;
  const int fb = kk * 32 + (l >> 4) * 8;
  const int n = nt * 16 + (l & 15);
  bf16x8 v;
#pragma unroll
  for (int j = 0; j < 8; ++j) v[j] = (bf16_t)W2[(fb + j) * E_ + n];
  *reinterpret_cast<bf16x8*>(w2sw + (size_t)q * 8) = v;
}

// ---- fused (R10 body, XCD-swizzled grid, compact code) ----
__global__ __launch_bounds__(256, 4) void fused_kernel(const float* __restrict__ x,
                                                       const float* __restrict__ W1,
                                                       const float* __restrict__ b1,
                                                       const bf16_t* __restrict__ w2sw,
                                                       const float* __restrict__ b2,
                                                       float* __restrict__ out) {
  __shared__ bf16_t et[E_ * SLP];   // 25.6 KB
  const int tid = threadIdx.x;
  // XCD swizzle: 1024 blocks = 8 XCDs x 128; XCD k gets logical 128k..128k+127
  // = batches 4k..4k+3 (all 32 t-tiles each) -> x/out locality per XCD.
  const int logical = ((blockIdx.x & 7) << 7) + (blockIdx.x >> 3);
  const int b = logical >> 5;
  const int t0 = (logical & 31) * TT;
  const int lane = tid & 63;
  const int wv = tid >> 6;              // n-quarter 0..3
  const int l15 = lane & 15;
  const int g = lane >> 4;

  // ---- e-build: thread = (d-group of 8, s-lane of 32) x 5 slots ----
  const int dg = tid >> 5;
  const int sg = tid & 31;
  const int s0 = 4 * t0;
  float xv[V_][5];
#pragma unroll
  for (int v = 0; v < V_; ++v) {
    const float* xb = x + ((size_t)(b * V_ + v) << 12);
#pragma unroll
    for (int k = 0; k < 5; ++k) {
      int s = s0 + sg + 32 * k;
      if (s > S_ - 1) s = S_ - 1;       // clamp: only masked-token region affected
      xv[v][k] = xb[s];
    }
  }
#pragma unroll 2
  for (int dd = 0; dd < 8; ++dd) {
    const int d = dg * 8 + dd;
    const float bb = b1[d];
    float acc[5];
#pragma unroll
    for (int k = 0; k < 5; ++k) acc[k] = bb;
#pragma unroll
    for (int v = 0; v < V_; ++v) {
      const float w = W1[v * E_ + d];
#pragma unroll
      for (int k = 0; k < 5; ++k) acc[k] += xv[v][k] * w;
    }
#pragma unroll
    for (int k = 0; k < 5; ++k)
      et[d * SLP + sg + 32 * k] = (bf16_t)floorf(acc[k]);
  }
  __syncthreads();

  // ---- K-loop: A from LDS e-tile; B streamed from w2sw; compact unroll 4 ----
  const char* etb = reinterpret_cast<const char*>(et);
  const uint32_t aoff = 400u * (g >> 1) + 8u * l15 + 16u * (g & 1);  // +800/kk, +128/mt
  const bf16_t* bptr = w2sw + (((size_t)wv * 64 + lane) << 3);       // +2048 elems per kk
  const float bv = b2[wv * 16 + l15];
  f32x4 acc0 = {bv, bv, bv, bv};
  f32x4 acc1 = {bv, bv, bv, bv};
#pragma unroll 4
  for (int kk = 0; kk < 32; ++kk) {
    const char* pa = etb + aoff + 800 * kk;
    union { u64 q[2]; bf16x8 v; } A0, A1;
    A0.q[0] = *reinterpret_cast<const u64*>(pa);
    A0.q[1] = *reinterpret_cast<const u64*>(pa + 8);
    A1.q[0] = *reinterpret_cast<const u64*>(pa + 128);
    A1.q[1] = *reinterpret_cast<const u64*>(pa + 136);
    const bf16x8 Bf = *reinterpret_cast<const bf16x8*>(bptr + ((size_t)kk << 11));
    acc0 = __builtin_amdgcn_mfma_f32_16x16x32_bf16(A0.v, Bf, acc0, 0, 0, 0);
    acc1 = __builtin_amdgcn_mfma_f32_16x16x32_bf16(A1.v, Bf, acc1, 0, 0, 0);
  }
  // ---- epilogue: D row = g*4+r (token), col = l15 (n); nontemporal stores ----
#pragma unroll
  for (int r = 0; r < 4; ++r) {
    const int t1 = t0 + g * 4 + r;
    if (t1 < T_)
      __builtin_nontemporal_store(floorf(acc0[r]),
                                  &out[((size_t)(b * T_ + t1)) * E_ + wv * 16 + l15]);
    const int t2 = t0 + 16 + g * 4 + r;
    if (t2 < T_)
      __builtin_nontemporal_store(floorf(acc1[r]),
                                  &out[((size_t)(b * T_ + t2)) * E_ + wv * 16 + l15]);
  }
}

extern "C" void kernel_launch(void* const* d_in, const int* in_sizes, int n_in,
                              void* d_out, int out_size, void* d_ws, size_t ws_size,
                              hipStream_t stream) {
  const float* x  = (const float*)d_in[0];
  const float* W1 = (const float*)d_in[1];
  const float* b1 = (const float*)d_in[2];
  const float* W2 = (const float*)d_in[3];
  const float* b2 = (const float*)d_in[4];
  float* out = (float*)d_out;

  bf16_t* w2sw = (bf16_t*)d_ws;   // 128 KiB swizzled bf16 W2

  hipLaunchKernelGGL(prep_kernel, dim3(32), dim3(256), 0, stream, W2, w2sw);
  hipLaunchKernelGGL(fused_kernel, dim3(1024), dim3(256), 0, stream,
                     x, W1, b1, w2sw, b2, out);
}

// Round 14
// 20.602 us; speedup vs baseline: 1.1249x; 1.0647x over previous
//
#include <hip/hip_runtime.h>
#include <cstdint>
#include <cstddef>

#define B_ 32
#define V_ 8
#define S_ 4096
#define E_ 64
#define T_ 1020     // len(arange(0, S-WIN, STEP))
#define TT 32       // tokens per block
#define SLP 200     // e-tile row stride (need >=140 cols)

typedef __bf16 bf16_t;
typedef bf16_t bf16x8 __attribute__((ext_vector_type(8)));
typedef float f32x4 __attribute__((ext_vector_type(4)));

// ---- prep: w2sw swizzled bf16 so a wave's B-fragment is one coalesced 1KB load ----
// elem index i = ((kk*4 + nt)*64 + l)*8 + j  holds  W2[f = kk*32 + (l>>4)*8 + j][n = nt*16 + (l&15)]
__global__ __launch_bounds__(256) void prep_kernel(const float* __restrict__ W2,
                                                   bf16_t* __restrict__ w2sw) {
  const int q = blockIdx.x * 256 + threadIdx.x;      // 8192 quads of 8 elems
  const int l = q & 63, nt = (q >> 6) & 3, kk = q >> 8;
  const int fb = kk * 32 + (l >> 4) * 8;
  const int n = nt * 16 + (l & 15);
  bf16x8 v;
#pragma unroll
  for (int j = 0; j < 8; ++j) v[j] = (bf16_t)W2[(fb + j) * E_ + n];
  *reinterpret_cast<bf16x8*>(w2sw + (size_t)q * 8) = v;
}

// ---- fused (R10 == session best, 20.4 us): e-tile build + barrier-free K-loop ----
// (1) B[kk<8] preload attempt retained (harmless; compiler may sink);
// (2) unroll 8 on streamed K-loop (8 B-loads in flight — load-bearing);
// (3) nontemporal out stores (no RFO).
__global__ __launch_bounds__(256, 4) void fused_kernel(const float* __restrict__ x,
                                                       const float* __restrict__ W1,
                                                       const float* __restrict__ b1,
                                                       const bf16_t* __restrict__ w2sw,
                                                       const float* __restrict__ b2,
                                                       float* __restrict__ out) {
  __shared__ bf16_t et[E_ * SLP];   // 25.6 KB
  const int tid = threadIdx.x;
  const int b = blockIdx.y;
  const int t0 = blockIdx.x * TT;
  const int lane = tid & 63;
  const int wv = tid >> 6;              // n-quarter 0..3
  const int l15 = lane & 15;
  const int g = lane >> 4;
  const bf16_t* bptr = w2sw + (((size_t)wv * 64 + lane) << 3);   // +2048 elems per kk

  // ---- issue x loads (e-build inputs) ----
  const int dg = tid >> 5;
  const int sg = tid & 31;
  const int s0 = 4 * t0;
  float xv[V_][5];
#pragma unroll
  for (int v = 0; v < V_; ++v) {
#pragma unroll
    for (int k = 0; k < 5; ++k) {
      int s = s0 + sg + 32 * k;
      if (s > S_ - 1) s = S_ - 1;       // clamp: only masked-token region affected
      xv[v][k] = x[((size_t)(b * V_ + v) << 12) + s];
    }
  }
  // ---- pre-barrier B preload: kk = 0..7 ----
  bf16x8 Bpre[8];
#pragma unroll
  for (int kk = 0; kk < 8; ++kk)
    Bpre[kk] = *reinterpret_cast<const bf16x8*>(bptr + ((size_t)kk << 11));
  const float bv = b2[wv * 16 + l15];

  // ---- e-build: thread = (d-group of 8, s-lane of 32) x 5 slots ----
#pragma unroll
  for (int dd = 0; dd < 8; ++dd) {
    const int d = dg * 8 + dd;
    const float bb = b1[d];
    float acc[5];
#pragma unroll
    for (int k = 0; k < 5; ++k) acc[k] = bb;
#pragma unroll
    for (int v = 0; v < V_; ++v) {
      const float w = W1[v * E_ + d];
#pragma unroll
      for (int k = 0; k < 5; ++k) acc[k] += xv[v][k] * w;
    }
#pragma unroll
    for (int k = 0; k < 5; ++k)
      et[d * SLP + sg + 32 * k] = (bf16_t)floorf(acc[k]);
  }
  __syncthreads();

  // ---- K-loop: A from LDS e-tile; B from Bpre (kk<8) then streamed (kk>=8) ----
  const char* etb = reinterpret_cast<const char*>(et);
  const uint32_t aoff = 400u * (g >> 1) + 8u * l15 + 16u * (g & 1);  // +800/kk, +128/mt
  f32x4 acc0 = {bv, bv, bv, bv};
  f32x4 acc1 = {bv, bv, bv, bv};
#pragma unroll
  for (int kk = 0; kk < 8; ++kk) {
    const char* pa = etb + aoff + 800 * kk;
    union { uint64_t q[2]; bf16x8 v; } A0, A1;
    A0.q[0] = *reinterpret_cast<const uint64_t*>(pa);
    A0.q[1] = *reinterpret_cast<const uint64_t*>(pa + 8);
    A1.q[0] = *reinterpret_cast<const uint64_t*>(pa + 128);
    A1.q[1] = *reinterpret_cast<const uint64_t*>(pa + 136);
    acc0 = __builtin_amdgcn_mfma_f32_16x16x32_bf16(A0.v, Bpre[kk], acc0, 0, 0, 0);
    acc1 = __builtin_amdgcn_mfma_f32_16x16x32_bf16(A1.v, Bpre[kk], acc1, 0, 0, 0);
  }
#pragma unroll 8
  for (int kk = 8; kk < 32; ++kk) {
    const char* pa = etb + aoff + 800 * kk;
    union { uint64_t q[2]; bf16x8 v; } A0, A1;
    A0.q[0] = *reinterpret_cast<const uint64_t*>(pa);
    A0.q[1] = *reinterpret_cast<const uint64_t*>(pa + 8);
    A1.q[0] = *reinterpret_cast<const uint64_t*>(pa + 128);
    A1.q[1] = *reinterpret_cast<const uint64_t*>(pa + 136);
    const bf16x8 Bf = *reinterpret_cast<const bf16x8*>(bptr + ((size_t)kk << 11));
    acc0 = __builtin_amdgcn_mfma_f32_16x16x32_bf16(A0.v, Bf, acc0, 0, 0, 0);
    acc1 = __builtin_amdgcn_mfma_f32_16x16x32_bf16(A1.v, Bf, acc1, 0, 0, 0);
  }
  // ---- epilogue: D row = g*4+r (token), col = l15 (n); nontemporal stores ----
#pragma unroll
  for (int r = 0; r < 4; ++r) {
    const int t1 = t0 + g * 4 + r;
    if (t1 < T_)
      __builtin_nontemporal_store(floorf(acc0[r]),
                                  &out[((size_t)(b * T_ + t1)) * E_ + wv * 16 + l15]);
    const int t2 = t0 + 16 + g * 4 + r;
    if (t2 < T_)
      __builtin_nontemporal_store(floorf(acc1[r]),
                                  &out[((size_t)(b * T_ + t2)) * E_ + wv * 16 + l15]);
  }
}

extern "C" void kernel_launch(void* const* d_in, const int* in_sizes, int n_in,
                              void* d_out, int out_size, void* d_ws, size_t ws_size,
                              hipStream_t stream) {
  const float* x  = (const float*)d_in[0];
  const float* W1 = (const float*)d_in[1];
  const float* b1 = (const float*)d_in[2];
  const float* W2 = (const float*)d_in[3];
  const float* b2 = (const float*)d_in[4];
  float* out = (float*)d_out;

  bf16_t* w2sw = (bf16_t*)d_ws;   // 128 KiB swizzled bf16 W2

  hipLaunchKernelGGL(prep_kernel, dim3(32), dim3(256), 0, stream, W2, w2sw);
  hipLaunchKernelGGL(fused_kernel, dim3((T_ + TT - 1) / TT, B_), dim3(256), 0, stream,
                     x, W1, b1, w2sw, b2, out);
}